// Round 10
// baseline (351.245 us; speedup 1.0000x reference)
//
#include <hip/hip_runtime.h>
#include <hip/hip_cooperative_groups.h>
#include <stdint.h>
#include <math.h>

namespace cg = cooperative_groups;

// ---------------------------------------------------------------------------
// IID segmentation loss on MI355X.  Round 12.
// R11 confirmed the bank-pad model (conflicts 7.0M->2.0M, corr 54.6us, best
// total 146.5). Remaining: non-corr share ~92us, INVARIANT across all tail
// restructures, vs ~18us of hand-computed tail kernel work -> hypothesis:
// launch/gap/dependency overhead of 4 serial dispatches. R12 tests it
// directly: ONE cooperative kernel (grid 256 x 640 = exactly 1 block/CU at
// 152576B LDS), grid.sync() between phases (sanctioned cross-XCD fence):
//   P1 prep_b (grid-stride), P2 corr (R11 verbatim), P3 reduce (100 cells/
//   block, 4x64-grid groups), P4 loss (blocks 0-224).
// Null result (~145) would prove the tail is harness-fixed overhead.
// ---------------------------------------------------------------------------

#define PADV 7
#define TS 15
#define KCLS 10
#define HH 224
#define WW 224
#define MD 160
#define NCELL (MD*MD)
#define NBLK 256
#define TY 14
#define BSTRIDE 232          // global bpad row stride (elems)
#define BSTRIDE_L 236        // LDS B row stride (elems): 118 dw == 22 mod 32
#define BPH 240
#define PLANEE 2408          // elems per shift-plane (10*240 + 8 pad)
#define ABUFE (8*PLANEE)     // elems per A buffer (8 planes)
#define LDSA_BYTES (2*ABUFE*2)              // 77056
#define LDSB_L_BYTES (KCLS*16*BSTRIDE_L*2)  // 75520
#define SMEM_BYTES (LDSA_BYTES + LDSB_L_BYTES)  // 152576
#define NPREP (38400*29)     // prep items: 160 cls-rows*240 yy * 29 chunks
#define LEPS 1e-16

typedef __attribute__((ext_vector_type(4))) float f32x4;
typedef __attribute__((ext_vector_type(8))) short bf16x8;

__device__ __forceinline__ unsigned short f2bf(float f) {
  union { float f; uint32_t u; } v; v.f = f;
  return (unsigned short)((v.u + 0x7FFFu + ((v.u >> 16) & 1u)) >> 16);
}

__device__ __forceinline__ uint32_t pack2bf(float a, float b) {
  return (uint32_t)f2bf(a) | ((uint32_t)f2bf(b) << 16);
}

__device__ __forceinline__ void glds16(const unsigned short* g, unsigned short* l) {
  __builtin_amdgcn_global_load_lds(
      (const __attribute__((address_space(1))) unsigned int*)g,
      (__attribute__((address_space(3))) unsigned int*)l, 16, 0, 0);
}

// Write the 8 shift-planes for one (class, 8-elem chunk) from 16 loaded f32.
__device__ __forceinline__ void plane_write(const f32x4 f[4], unsigned short* awr) {
  uint32_t w[8];
#pragma unroll
  for (int k = 0; k < 8; ++k)
    w[k] = pack2bf(f[k >> 1][(k & 1) * 2], f[k >> 1][(k & 1) * 2 + 1]);
#pragma unroll
  for (int c = 0; c < 8; ++c) {
    union { uint32_t u[4]; uint4 v; } o;
    if (c & 1) {
#pragma unroll
      for (int j = 0; j < 4; ++j) o.u[j] = w[j + (c + 1) / 2];
    } else {
#pragma unroll
      for (int j = 0; j < 4; ++j)
        o.u[j] = __builtin_amdgcn_alignbit(w[j + 1 + c / 2], w[j + c / 2], 16);
    }
    *(uint4*)(awr + c * PLANEE) = o.v;
  }
}

#define MFMA_BF16 __builtin_amdgcn_mfma_f32_16x16x32_bf16

__global__ __launch_bounds__(640, 1)
void fused_all(const float* __restrict__ xo, const float* __restrict__ xt,
               unsigned short* __restrict__ bpad, float* __restrict__ partials,
               float* __restrict__ Cmat, float* __restrict__ mins,
               float* __restrict__ dout) {
  __shared__ __align__(16) unsigned char smem[SMEM_BYTES];
  cg::grid_group grid = cg::this_grid();
  const int tid = threadIdx.x;

  // ===== Phase 1: prep_b (grid-stride over 1,113,600 items) =====
  for (int idx = blockIdx.x * 640 + tid; idx < NPREP; idx += NBLK * 640) {
    const int rowid = idx / 29;
    const int chunk = idx - rowid * 29;
    const int x0    = chunk * 8;
    const int yy    = rowid % BPH;
    const int cls   = rowid / BPH;
    const int row   = yy - PADV;
    union { unsigned short h[8]; uint4 v; } out;
    if (row >= 0 && row < HH && chunk < 28) {
      const float4* src = (const float4*)(xt + ((size_t)cls * HH + row) * WW + x0);
      const float4 f0 = src[0], f1 = src[1];
      out.h[0] = f2bf(f0.x); out.h[1] = f2bf(f0.y);
      out.h[2] = f2bf(f0.z); out.h[3] = f2bf(f0.w);
      out.h[4] = f2bf(f1.x); out.h[5] = f2bf(f1.y);
      out.h[6] = f2bf(f1.z); out.h[7] = f2bf(f1.w);
    } else {
      out.v = make_uint4(0u, 0u, 0u, 0u);
    }
    *(uint4*)(bpad + (size_t)rowid * BSTRIDE + x0) = out.v;
  }
  grid.sync();

  // ===== Phase 2: corr_gemm (R11 verbatim) =====
  {
    unsigned short* const ldsA8 = (unsigned short*)smem;
    unsigned short* const ldsB  = (unsigned short*)(smem + LDSA_BYTES);

    const int bid0 = blockIdx.x;
    const int bid  = (bid0 & 7) * 32 + (bid0 >> 3);
    const int b    = bid >> 4;           // 16 batches
    const int y0   = (bid & 15) * TY;    // 16 groups of 14 rows

    const int lane = tid & 63;
    const int wv   = tid >> 6;
    const int wm   = wv >> 1;
    const int wn   = wv & 1;
    const int quad = lane >> 4;
    const int l15  = lane & 15;

    f32x4 acc[2][5];
#pragma unroll
    for (int i = 0; i < 2; ++i)
#pragma unroll
      for (int j = 0; j < 5; ++j) acc[i][j] = (f32x4){0.f, 0.f, 0.f, 0.f};

    const float* Ab = xo + (size_t)b * KCLS * HH * WW;
    const unsigned short* Bb = bpad + (size_t)b * KCLS * BPH * BSTRIDE;

    const bool aw  = tid < 300;
    const int an   = aw ? tid / 30 : 0;
    const int atp  = aw ? tid - (tid / 30) * 30 : 0;
    const int axb  = atp * 8 - 8;
    bool gv[4];
#pragma unroll
    for (int g = 0; g < 4; ++g)
      gv[g] = aw && (axb + 4 * g >= 0) && (axb + 4 * g + 4 <= WW);
    unsigned short* const awr0 = ldsA8 + an * 240 + atp * 8;

    for (int pr = wv; pr < 15 * KCLS; pr += 10) {
      const int r15  = pr / KCLS;
      const int o    = pr - r15 * KCLS;
      const int yy   = y0 + r15;
      const int slot = (y0 - PADV + r15) & 15;
      if (lane < 29)
        glds16(Bb + ((size_t)o * BPH + yy) * BSTRIDE + lane * 8,
               ldsB + (o * 16 + slot) * BSTRIDE_L);
    }

    f32x4 f[4];
    {
      const float* src = Ab + ((size_t)an * HH + y0) * WW + axb;
#pragma unroll
      for (int g = 0; g < 4; ++g) {
        f[g] = (f32x4){0.f, 0.f, 0.f, 0.f};
        if (gv[g]) f[g] = *(const f32x4*)(src + 4 * g);
      }
    }
    if (aw) plane_write(f, awr0);
    __syncthreads();  // drains B prologue DMA + publishes A planes (buf 0)

    int cur = 0;
    for (int s = 0; s < TY; ++s) {
      const int y = y0 + s;
      const bool more = (s + 1 < TY);

      if (more) {
        const int yy   = y + 8 + PADV;
        const int slot = (y + 8) & 15;
        if (lane < 29)
          glds16(Bb + ((size_t)wv * BPH + yy) * BSTRIDE + lane * 8,
                 ldsB + (wv * 16 + slot) * BSTRIDE_L);
        const float* src = Ab + ((size_t)an * HH + (y + 1)) * WW + axb;
#pragma unroll
        for (int g = 0; g < 4; ++g) {
          f[g] = (f32x4){0.f, 0.f, 0.f, 0.f};
          if (gv[g]) f[g] = *(const f32x4*)(src + 4 * g);
        }
      }

      const unsigned short* paB = ldsA8 + cur * ABUFE + (l15 & 7) * PLANEE + (l15 & 8);
      const int slotB = (y + PADV - l15) & 15;

#pragma unroll 2
      for (int xc = 0; xc < 7; ++xc) {
        const int x0 = xc * 32;
        bf16x8 afrag[2], bfrag[5];
#pragma unroll
        for (int mi = 0; mi < 2; ++mi)
          afrag[mi] = *(const bf16x8*)(paB + (wm * 2 + mi) * 240 + x0 + quad * 8);
#pragma unroll
        for (int ni = 0; ni < 5; ++ni) {
          const int to = wn * 5 + ni;
          bfrag[ni] = *(const bf16x8*)(ldsB + (to * 16 + slotB) * BSTRIDE_L + x0 + quad * 8);
        }
#pragma unroll
        for (int mi = 0; mi < 2; ++mi)
#pragma unroll
          for (int ni = 0; ni < 5; ++ni)
            acc[mi][ni] = MFMA_BF16(afrag[mi], bfrag[ni], acc[mi][ni], 0, 0, 0);
      }

      if (more) {
        if (aw) plane_write(f, awr0 + (cur ^ 1) * ABUFE);
        __syncthreads();  // drains B DMA + publishes A planes (buf cur^1)
        cur ^= 1;
      }
    }

    float* outp = partials + (size_t)bid * NCELL;
#pragma unroll
    for (int mi = 0; mi < 2; ++mi)
#pragma unroll
      for (int ni = 0; ni < 5; ++ni) {
        const int mrow = (wm * 2 + mi) * 16 + quad * 4;
        const int ncol = (wn * 5 + ni) * 16 + l15;
#pragma unroll
        for (int r = 0; r < 4; ++r)
          outp[(size_t)(mrow + r) * MD + ncol] = acc[mi][ni][r];
      }
  }
  grid.sync();

  // ===== Phase 3: reduce (block -> 100 cells; 4 grid-groups of 64) =====
  {
    double* redd = (double*)smem;             // 400 doubles
    float*  redm = (float*)(smem + 4096);     // 128 floats
    if (blockIdx.x == 0 && tid == 0) dout[0] = 0.f;
    const int c0 = blockIdx.x * 100;
    if (tid < 400) {
      const int g  = tid / 100;
      const int cl = tid - g * 100;
      const float* base = partials + (size_t)g * 64 * NCELL + c0 + cl;
      double s0 = 0.0, s1 = 0.0, s2 = 0.0, s3 = 0.0;
      for (int p = 0; p < 64; p += 4) {
        s0 += (double)base[(size_t)(p + 0) * NCELL];
        s1 += (double)base[(size_t)(p + 1) * NCELL];
        s2 += (double)base[(size_t)(p + 2) * NCELL];
        s3 += (double)base[(size_t)(p + 3) * NCELL];
      }
      redd[tid] = (s0 + s1) + (s2 + s3);
    }
    __syncthreads();
    if (tid < 128) {
      float mv = 3.4e38f;
      if (tid < 100) {
        const double tot = redd[tid] + redd[tid + 100] + redd[tid + 200] + redd[tid + 300];
        const float sf = (float)tot;
        const int c = c0 + tid;
        Cmat[c] = sf;
        const int m  = c / MD;
        const int nn = c - m * MD;
        if (((m & 15) < TS) && ((nn & 15) < TS)) mv = sf;
      }
      redm[tid] = mv;
    }
    __syncthreads();
    for (int st = 64; st > 0; st >>= 1) {
      if (tid < st) redm[tid] = fminf(redm[tid], redm[tid + st]);
      __syncthreads();
    }
    if (tid == 0) mins[blockIdx.x] = redm[0];
  }
  grid.sync();

  // ===== Phase 4: loss (blocks 0..224, one shift each) =====
  if (blockIdx.x < TS * TS) {
    float*  fm  = (float*)smem;                // 512 B
    double* q   = (double*)(smem + 512);       // 800 B
    double* sym = (double*)(smem + 1536);      // 800 B
    double* pi  = (double*)(smem + 2560);      // 80 B
    double* pj  = (double*)(smem + 2688);      // 80 B
    double* red = (double*)(smem + 2816);      // 1024 B

    const int s  = blockIdx.x;
    const int dy = s / TS;
    const int dx = s - dy * TS;

    if (tid < 128) {
      float v = 3.4e38f;
      for (int i = tid; i < NBLK; i += 128) v = fminf(v, mins[i]);
      fm[tid] = v;
    }
    __syncthreads();
    for (int st = 64; st > 0; st >>= 1) {
      if (tid < st) fm[tid] = fminf(fm[tid], fm[tid + st]);
      __syncthreads();
    }
    const double minv = (double)fm[0];
    __syncthreads();

    if (tid < 100) {
      const int n = tid / 10, o = tid - (tid / 10) * 10;
      const double v = (double)Cmat[(size_t)(n * 16 + dx) * MD + (o * 16 + dy)];
      q[tid] = v - minv + LEPS;
    }
    __syncthreads();
    if (tid < 128) red[tid] = (tid < 100) ? q[tid] : 0.0;
    __syncthreads();
    for (int st = 64; st > 0; st >>= 1) {
      if (tid < st) red[tid] += red[tid + st];
      __syncthreads();
    }
    const double Z = red[0];
    __syncthreads();
    if (tid < 100) {
      const int n = tid / 10, o = tid - (tid / 10) * 10;
      sym[tid] = (q[n * 10 + o] + q[o * 10 + n]) * 0.5 / Z;
    }
    __syncthreads();
    if (tid < 10) {
      double a = 0.0, bsum = 0.0;
      for (int n2 = 0; n2 < 10; ++n2) {
        a    += sym[n2 * 10 + tid];
        bsum += sym[tid * 10 + n2];
      }
      pi[tid] = a;
      pj[tid] = bsum;
    }
    __syncthreads();
    if (tid < 128) {
      double term = 0.0;
      if (tid < 100) {
        const int n = tid / 10, o = tid - (tid / 10) * 10;
        const double sp = sym[tid];
        term = -sp * (log(sp + LEPS) - log(pi[o] + LEPS) - log(pj[n] + LEPS));
      }
      red[tid] = term;
    }
    __syncthreads();
    for (int st = 64; st > 0; st >>= 1) {
      if (tid < st) red[tid] += red[tid + st];
      __syncthreads();
    }
    if (tid == 0) atomicAdd(dout, (float)(red[0] / (double)(TS * TS)));
  }
}

extern "C" void kernel_launch(void* const* d_in, const int* in_sizes, int n_in,
                              void* d_out, int out_size, void* d_ws, size_t ws_size,
                              hipStream_t stream) {
  const float* xo = (const float*)d_in[0];
  const float* xt = (const float*)d_in[1];
  float* ws       = (float*)d_ws;

  float* partials = ws;
  float* Cmat     = partials + (size_t)NBLK * NCELL;
  float* mins     = Cmat + NCELL;
  unsigned short* bpad = (unsigned short*)(mins + 512);
  float* out      = (float*)d_out;

  void* args[] = {(void*)&xo, (void*)&xt, (void*)&bpad, (void*)&partials,
                  (void*)&Cmat, (void*)&mins, (void*)&out};
  hipLaunchCooperativeKernel((const void*)fused_all, dim3(NBLK), dim3(640),
                             args, 0, stream);
}

// Round 11
// 257.791 us; speedup vs baseline: 1.3625x; 1.3625x over previous
//
#include <hip/hip_runtime.h>
#include <stdint.h>
#include <math.h>

// ---------------------------------------------------------------------------
// IID segmentation loss on MI355X.  Round 13.
// R12: grid.sync() ~65us each on 256-block grid -> cooperative fusion dead;
// also proved ~60-70us of bench total is fixed harness overhead (single
// dispatch still showed it). Revert to R11 4-kernel pipeline (146.5 best).
// This round: 32x32x16 MFMA retile of corr (halves fragment reads per FLOP).
// 25 tiles of 32x32; 10 waves = 2 K-groups (ksteps 0-6/7-13, uniform code)
// x 5 waves; wave owns M-band x 5 N-bands: per kstep 1 A-read + 5 B-reads
// + 5 MFMAs. acc = five named f32x16 (SROA-safe; R9 held 80 regs clean).
// Reads/row 490->420, MFMA cyc 3400->2800. Bank math verified (A planes
// 20c mod 32 full cover; B slots 22s mod 32 distinct). Cross-K combine via
// proven LDS-overlay epilogue. Tail = R7/R11 verbatim.
// ---------------------------------------------------------------------------

#define PADV 7
#define TS 15
#define KCLS 10
#define HH 224
#define WW 224
#define MD 160
#define NCELL (MD*MD)
#define NBLK 256
#define TY 14
#define BSTRIDE 232          // global bpad row stride (elems)
#define BSTRIDE_L 236        // LDS B row stride (elems): 118 dw == 22 mod 32
#define BPH 240
#define PLANEE 2408          // elems per shift-plane (10*240 + 8 pad)
#define ABUFE (8*PLANEE)     // elems per A buffer (8 planes)
#define LDSA_BYTES (2*ABUFE*2)              // 77056
#define LDSB_L_BYTES (KCLS*16*BSTRIDE_L*2)  // 75520
#define SMEM_BYTES (LDSA_BYTES + LDSB_L_BYTES)  // 152576
#define NRED 400
#define LEPS 1e-16

typedef __attribute__((ext_vector_type(4))) float f32x4;
typedef __attribute__((ext_vector_type(16))) float f32x16;
typedef __attribute__((ext_vector_type(8))) short bf16x8;

__device__ __forceinline__ unsigned short f2bf(float f) {
  union { float f; uint32_t u; } v; v.f = f;
  return (unsigned short)((v.u + 0x7FFFu + ((v.u >> 16) & 1u)) >> 16);
}

__device__ __forceinline__ uint32_t pack2bf(float a, float b) {
  return (uint32_t)f2bf(a) | ((uint32_t)f2bf(b) << 16);
}

__device__ __forceinline__ void glds16(const unsigned short* g, unsigned short* l) {
  __builtin_amdgcn_global_load_lds(
      (const __attribute__((address_space(1))) unsigned int*)g,
      (__attribute__((address_space(3))) unsigned int*)l, 16, 0, 0);
}

// Write the 8 shift-planes for one (class, 8-elem chunk) from 16 loaded f32.
__device__ __forceinline__ void plane_write(const f32x4 f[4], unsigned short* awr) {
  uint32_t w[8];
#pragma unroll
  for (int k = 0; k < 8; ++k)
    w[k] = pack2bf(f[k >> 1][(k & 1) * 2], f[k >> 1][(k & 1) * 2 + 1]);
#pragma unroll
  for (int c = 0; c < 8; ++c) {
    union { uint32_t u[4]; uint4 v; } o;
    if (c & 1) {
#pragma unroll
      for (int j = 0; j < 4; ++j) o.u[j] = w[j + (c + 1) / 2];
    } else {
#pragma unroll
      for (int j = 0; j < 4; ++j)
        o.u[j] = __builtin_amdgcn_alignbit(w[j + 1 + c / 2], w[j + c / 2], 16);
    }
    *(uint4*)(awr + c * PLANEE) = o.v;
  }
}

// Bpad[cls][yy][x]: cls=b*10+o, yy in [0,240) <-> row=yy-7, x in [0,232).
__global__ __launch_bounds__(256)
void prep_b(const float* __restrict__ xt, unsigned short* __restrict__ bp) {
  const int idx   = blockIdx.x * 256 + threadIdx.x;
  const int rowid = idx / 29;
  const int chunk = idx - rowid * 29;
  const int x0    = chunk * 8;
  const int yy    = rowid % BPH;
  const int cls   = rowid / BPH;
  const int row   = yy - PADV;
  union { unsigned short h[8]; uint4 v; } out;
  if (row >= 0 && row < HH && chunk < 28) {
    const float4* src = (const float4*)(xt + ((size_t)cls * HH + row) * WW + x0);
    const float4 f0 = src[0], f1 = src[1];
    out.h[0] = f2bf(f0.x); out.h[1] = f2bf(f0.y);
    out.h[2] = f2bf(f0.z); out.h[3] = f2bf(f0.w);
    out.h[4] = f2bf(f1.x); out.h[5] = f2bf(f1.y);
    out.h[6] = f2bf(f1.z); out.h[7] = f2bf(f1.w);
  } else {
    out.v = make_uint4(0u, 0u, 0u, 0u);
  }
  *(uint4*)(bp + (size_t)rowid * BSTRIDE + x0) = out.v;
}

#define MFMA32 __builtin_amdgcn_mfma_f32_32x32x16_bf16

__global__ __launch_bounds__(640, 1)
void corr_gemm(const float* __restrict__ xo, const unsigned short* __restrict__ bpad,
               float* __restrict__ partials) {
  __shared__ __align__(16) unsigned char smem[SMEM_BYTES];
  unsigned short* const ldsA8 = (unsigned short*)smem;
  unsigned short* const ldsB  = (unsigned short*)(smem + LDSA_BYTES);
  float* const scratch        = (float*)smem;   // epilogue overlay (102.4KB)

  const int tid  = threadIdx.x;
  const int bid0 = blockIdx.x;
  // XCD-bijective swizzle (256 = 8*32).
  const int bid  = (bid0 & 7) * 32 + (bid0 >> 3);
  const int b    = bid >> 4;           // 16 batches
  const int y0   = (bid & 15) * TY;    // 16 groups of 14 rows

  const int lane = tid & 63;
  const int wv   = tid >> 6;           // 0..9
  const int kg   = (wv >= 5);          // K-group: ksteps 0-6 / 7-13
  const int w5   = kg ? wv - 5 : wv;   // M-band 0..4
  const int l15  = lane & 15;          // dxi (A) / dyi (B)
  const int oh   = (lane >> 4) & 1;    // class-half within 32-row/col band
  const int kh   = lane >> 5;          // k-half (0/1) within K=16

  // 5 tiles (M-band w5 x N-band t), each f32x16 accumulator. Named -> SROA-safe.
  f32x16 a0, a1, a2, a3, a4;
#pragma unroll
  for (int j = 0; j < 16; ++j) { a0[j]=0.f; a1[j]=0.f; a2[j]=0.f; a3[j]=0.f; a4[j]=0.f; }

  const float* Ab = xo + (size_t)b * KCLS * HH * WW;
  const unsigned short* Bb = bpad + (size_t)b * KCLS * BPH * BSTRIDE;

  // A-row loader geometry: threads 0..299 (waves 0-4).
  const bool aw  = tid < 300;
  const int an   = aw ? tid / 30 : 0;
  const int atp  = aw ? tid - (tid / 30) * 30 : 0;
  const int axb  = atp * 8 - 8;
  bool gv[4];
#pragma unroll
  for (int g = 0; g < 4; ++g)
    gv[g] = aw && (axb + 4 * g >= 0) && (axb + 4 * g + 4 <= WW);
  unsigned short* const awr0 = ldsA8 + an * 240 + atp * 8;

  // prologue: async preload B rows y0-7..y0+7 (150 class-rows, 15/wave)
  for (int pr = wv; pr < 15 * KCLS; pr += 10) {
    const int r15  = pr / KCLS;
    const int o    = pr - r15 * KCLS;
    const int yy   = y0 + r15;
    const int slot = (y0 - PADV + r15) & 15;
    if (lane < 29)
      glds16(Bb + ((size_t)o * BPH + yy) * BSTRIDE + lane * 8,
             ldsB + (o * 16 + slot) * BSTRIDE_L);
  }

  // prologue: A row y0 -> planes in buf 0
  f32x4 f[4];
  {
    const float* src = Ab + ((size_t)an * HH + y0) * WW + axb;
#pragma unroll
    for (int g = 0; g < 4; ++g) {
      f[g] = (f32x4){0.f, 0.f, 0.f, 0.f};
      if (gv[g]) f[g] = *(const f32x4*)(src + 4 * g);
    }
  }
  if (aw) plane_write(f, awr0);
  __syncthreads();  // drains B prologue DMA + publishes A planes (buf 0)

  const int ksB = kg ? 7 : 0;
  int cur = 0;
  for (int s = 0; s < TY; ++s) {
    const int y = y0 + s;
    const bool more = (s + 1 < TY);

    if (more) {
      // async DMA: B row y+8 into dead slot (one class-row per wave)
      const int yy   = y + 8 + PADV;
      const int slot = (y + 8) & 15;
      if (lane < 29)
        glds16(Bb + ((size_t)wv * BPH + yy) * BSTRIDE + lane * 8,
               ldsB + (wv * 16 + slot) * BSTRIDE_L);
      // issue A row y+1 global loads early
      const float* src = Ab + ((size_t)an * HH + (y + 1)) * WW + axb;
#pragma unroll
      for (int g = 0; g < 4; ++g) {
        f[g] = (f32x4){0.f, 0.f, 0.f, 0.f};
        if (gv[g]) f[g] = *(const f32x4*)(src + 4 * g);
      }
    }

    // per-lane bases. A: plane (dxi&7), +8 if dxi>=8, class row (2*w5+oh),
    // k-half offset kh*8: one aligned b128 per kstep, bank-balanced.
    const unsigned short* paA = ldsA8 + cur * ABUFE + (l15 & 7) * PLANEE +
                                (l15 & 8) + (2 * w5 + oh) * 240 + kh * 8;
    const int slotB = (y + PADV - l15) & 15;
    const unsigned short* pB = ldsB + (oh * 16 + slotB) * BSTRIDE_L + kh * 8;

#pragma unroll 1
    for (int ks = ksB; ks < ksB + 7; ++ks) {
      const int xq = ks * 16;
      const bf16x8 af = *(const bf16x8*)(paA + xq);
      const bf16x8 bf0 = *(const bf16x8*)(pB + 0 * 32 * BSTRIDE_L + xq);
      const bf16x8 bf1 = *(const bf16x8*)(pB + 1 * 32 * BSTRIDE_L + xq);
      const bf16x8 bf2 = *(const bf16x8*)(pB + 2 * 32 * BSTRIDE_L + xq);
      const bf16x8 bf3 = *(const bf16x8*)(pB + 3 * 32 * BSTRIDE_L + xq);
      const bf16x8 bf4 = *(const bf16x8*)(pB + 4 * 32 * BSTRIDE_L + xq);
      a0 = MFMA32(af, bf0, a0, 0, 0, 0);
      a1 = MFMA32(af, bf1, a1, 0, 0, 0);
      a2 = MFMA32(af, bf2, a2, 0, 0, 0);
      a3 = MFMA32(af, bf3, a3, 0, 0, 0);
      a4 = MFMA32(af, bf4, a4, 0, 0, 0);
    }

    if (more) {
      if (aw) plane_write(f, awr0 + (cur ^ 1) * ABUFE);
      __syncthreads();  // drains B DMA + publishes A planes (buf cur^1)
      cur ^= 1;
    }
  }

  // ---- epilogue: cross-K-group reduction via LDS overlay ----
  __syncthreads();  // last k-step reads complete before overlay writes
  if (kg == 1) {
#define EPI_ST(T, ARR)                                                        \
    _Pragma("unroll")                                                         \
    for (int p = 0; p < 4; ++p) {                                             \
      f32x4 v;                                                                \
      _Pragma("unroll")                                                       \
      for (int j = 0; j < 4; ++j) v[j] = ARR[4 * p + j];                      \
      *(f32x4*)(scratch + ((w5 * 5 + (T)) * 4 + p) * 256 + lane * 4) = v;     \
    }
    EPI_ST(0, a0) EPI_ST(1, a1) EPI_ST(2, a2) EPI_ST(3, a3) EPI_ST(4, a4)
#undef EPI_ST
  }
  __syncthreads();
  if (kg == 0) {
    float* outp = partials + (size_t)bid * NCELL;
    const int c32 = lane & 31;
#define EPI_WR(T, ARR)                                                        \
    _Pragma("unroll")                                                         \
    for (int p = 0; p < 4; ++p) {                                             \
      f32x4 v = *(const f32x4*)(scratch +                                     \
                 ((w5 * 5 + (T)) * 4 + p) * 256 + lane * 4);                  \
      _Pragma("unroll")                                                       \
      for (int j = 0; j < 4; ++j)                                             \
        outp[(size_t)(w5 * 32 + j + 8 * p + 4 * kh) * MD + (T) * 32 + c32] =  \
            v[j] + ARR[4 * p + j];                                            \
    }
    EPI_WR(0, a0) EPI_WR(1, a1) EPI_WR(2, a2) EPI_WR(3, a3) EPI_WR(4, a4)
#undef EPI_WR
  }
}

// Fused reduce: 400 blocks; thread (cl,g) sums grids [g*64,(g+1)*64) for
// cell c = bid*64+cl; LDS-combine 4 groups; per-block min.
__global__ __launch_bounds__(256)
void reduce_all(const float* __restrict__ partials, float* __restrict__ Cout,
                float* __restrict__ mins, float* __restrict__ dout) {
  const int tid = threadIdx.x;
  const int cl  = tid & 63;
  const int g   = tid >> 6;
  const int c   = blockIdx.x * 64 + cl;
  if (blockIdx.x == 0 && tid == 0) dout[0] = 0.f;

  const float* base = partials + (size_t)g * 64 * NCELL + c;
  double s0 = 0.0, s1 = 0.0, s2 = 0.0, s3 = 0.0;
  for (int p = 0; p < 64; p += 4) {
    s0 += (double)base[(size_t)(p + 0) * NCELL];
    s1 += (double)base[(size_t)(p + 1) * NCELL];
    s2 += (double)base[(size_t)(p + 2) * NCELL];
    s3 += (double)base[(size_t)(p + 3) * NCELL];
  }
  __shared__ double redd[256];
  redd[tid] = (s0 + s1) + (s2 + s3);
  __syncthreads();

  __shared__ float redm[64];
  if (tid < 64) {
    const double tot = redd[tid] + redd[tid + 64] + redd[tid + 128] + redd[tid + 192];
    const float sf = (float)tot;
    Cout[c] = sf;
    const int m  = c / MD;
    const int nn = c - m * MD;
    const bool valid = ((m & 15) < TS) && ((nn & 15) < TS);
    redm[tid] = valid ? sf : 3.4e38f;
  }
  __syncthreads();
  for (int st = 32; st > 0; st >>= 1) {
    if (tid < st) redm[tid] = fminf(redm[tid], redm[tid + st]);
    __syncthreads();
  }
  if (tid == 0) mins[blockIdx.x] = redm[0];
}

__global__ __launch_bounds__(128)
void loss_kernel(const float* __restrict__ Cmat, const float* __restrict__ mins,
                 float* __restrict__ dout) {
  const int s   = blockIdx.x;
  const int dy  = s / TS;
  const int dx  = s - dy * TS;
  const int tid = threadIdx.x;
  __shared__ float fm[128];
  __shared__ double q[100];
  __shared__ double sym[100];
  __shared__ double pi[10], pj[10];
  __shared__ double red[128];

  {
    float v = 3.4e38f;
    for (int i = tid; i < NRED; i += 128) v = fminf(v, mins[i]);
    fm[tid] = v;
  }
  __syncthreads();
  for (int st = 64; st > 0; st >>= 1) {
    if (tid < st) fm[tid] = fminf(fm[tid], fm[tid + st]);
    __syncthreads();
  }
  const double minv = (double)fm[0];
  __syncthreads();

  if (tid < 100) {
    const int n = tid / 10, o = tid - (tid / 10) * 10;
    const double v = (double)Cmat[(size_t)(n * 16 + dx) * MD + (o * 16 + dy)];
    q[tid] = v - minv + LEPS;
  }
  __syncthreads();
  red[tid] = (tid < 100) ? q[tid] : 0.0;
  __syncthreads();
  for (int st = 64; st > 0; st >>= 1) {
    if (tid < st) red[tid] += red[tid + st];
    __syncthreads();
  }
  const double Z = red[0];
  __syncthreads();
  if (tid < 100) {
    const int n = tid / 10, o = tid - (tid / 10) * 10;
    sym[tid] = (q[n * 10 + o] + q[o * 10 + n]) * 0.5 / Z;
  }
  __syncthreads();
  if (tid < 10) {
    double a = 0.0, bsum = 0.0;
    for (int n2 = 0; n2 < 10; ++n2) {
      a    += sym[n2 * 10 + tid];
      bsum += sym[tid * 10 + n2];
    }
    pi[tid] = a;
    pj[tid] = bsum;
  }
  __syncthreads();
  double term = 0.0;
  if (tid < 100) {
    const int n = tid / 10, o = tid - (tid / 10) * 10;
    const double sp = sym[tid];
    term = -sp * (log(sp + LEPS) - log(pi[o] + LEPS) - log(pj[n] + LEPS));
  }
  red[tid] = term;
  __syncthreads();
  for (int st = 64; st > 0; st >>= 1) {
    if (tid < st) red[tid] += red[tid + st];
    __syncthreads();
  }
  if (tid == 0) atomicAdd(dout, (float)(red[0] / (double)(TS * TS)));
}

extern "C" void kernel_launch(void* const* d_in, const int* in_sizes, int n_in,
                              void* d_out, int out_size, void* d_ws, size_t ws_size,
                              hipStream_t stream) {
  const float* xo = (const float*)d_in[0];
  const float* xt = (const float*)d_in[1];
  float* ws       = (float*)d_ws;

  float* partials = ws;
  float* Cmat     = partials + (size_t)NBLK * NCELL;
  float* mins     = Cmat + NCELL;
  unsigned short* bpad = (unsigned short*)(mins + 512);
  float* out      = (float*)d_out;

  hipLaunchKernelGGL(prep_b,      dim3(4350), dim3(256), 0, stream, xt, bpad);
  hipLaunchKernelGGL(corr_gemm,   dim3(NBLK), dim3(640), 0, stream, xo, bpad, partials);
  hipLaunchKernelGGL(reduce_all,  dim3(NRED), dim3(256), 0, stream, partials, Cmat, mins, out);
  hipLaunchKernelGGL(loss_kernel, dim3(225),  dim3(128), 0, stream, Cmat, mins, out);
}